// Round 1
// baseline (1120.484 us; speedup 1.0000x reference)
//
#include <hip/hip_runtime.h>
#include <hip/hip_bf16.h>

typedef unsigned short u16;
typedef unsigned int u32;
typedef __attribute__((ext_vector_type(8))) short short8;
typedef __attribute__((ext_vector_type(4))) float f32x4;

#define DEVFN static __device__ __forceinline__

DEVFN u16 f2bf(float f) {
  union { float f; u32 i; } v; v.f = f;
  return (u16)((v.i + 0x7fffu + ((v.i >> 16) & 1u)) >> 16);
}

DEVFN void gload_lds16(const void* g, void* l) {
  __builtin_amdgcn_global_load_lds((const __attribute__((address_space(1))) u32*)g,
                                   (__attribute__((address_space(3))) u32*)l, 16, 0, 0);
}

// ---------------- weight transpose: W (K x N, f32) -> Wt (N x K, bf16) ----------
__global__ void wtrans_kernel(const float* __restrict__ w, u16* __restrict__ wt, int K, int N) {
  int idx = blockIdx.x * 256 + threadIdx.x;
  if (idx >= K * N) return;
  int n = idx / K, k = idx - n * K;
  wt[idx] = f2bf(w[(size_t)k * N + n]);
}

// ---------------- bias+mask table: [4 types][8 heads][64 n(key)][64 r(query)] ---
__global__ void biasmask_kernel(const float* __restrict__ rpb, float* __restrict__ bm) {
  int idx = blockIdx.x * 256 + threadIdx.x;
  if (idx >= 4 * 8 * 64 * 64) return;
  int r = idx & 63;
  int nn = (idx >> 6) & 63;
  int h = (idx >> 12) & 7;
  int t = idx >> 15;
  float v;
  if (nn >= 49) v = -1e9f;
  else if (r >= 49) v = 0.f;
  else {
    int i1 = r / 7, j1 = r - i1 * 7, i2 = nn / 7, j2 = nn - i2 * 7;
    int rel = (i1 - i2 + 6) * 13 + (j1 - j2 + 6);
    v = rpb[rel * 8 + h];
    int ry1 = (t & 2) ? (i1 < 4 ? 1 : 2) : 0;
    int rx1 = (t & 1) ? (j1 < 4 ? 1 : 2) : 0;
    int ry2 = (t & 2) ? (i2 < 4 ? 1 : 2) : 0;
    int rx2 = (t & 1) ? (j2 < 4 ? 1 : 2) : 0;
    if (ry1 * 3 + rx1 != ry2 * 3 + rx2) v += -100.0f;
  }
  bm[idx] = v;
}

// ---------------- LayerNorm (one wave per token); PERM = shift+window gather ----
template<bool PERM>
__global__ void ln_kernel(const float* __restrict__ x, const float* __restrict__ gg,
                          const float* __restrict__ bb, u16* __restrict__ out) {
  int gw = (int)(((u32)blockIdx.x * blockDim.x + threadIdx.x) >> 6);
  int lane = threadIdx.x & 63;
  size_t src;
  if (PERM) {
    u32 tw = (u32)gw;
    u32 b_ = tw / 49u, nn = tw - b_ * 49u;
    u32 bbi = b_ >> 6, wv = b_ & 63u, wy = wv >> 3, wx = wv & 7u;
    u32 ii = nn / 7u, jj = nn - ii * 7u;
    u32 y = wy * 7u + ii + 3u;  if (y >= 56u) y -= 56u;
    u32 xx = wx * 7u + jj + 3u; if (xx >= 56u) xx -= 56u;
    src = ((size_t)(bbi * 3136u + y * 56u + xx)) * 256u;
  } else {
    src = (size_t)gw * 256u;
  }
  float4 v = *(const float4*)(x + src + lane * 4);
  float s = v.x + v.y + v.z + v.w;
  float s2 = v.x * v.x + v.y * v.y + v.z * v.z + v.w * v.w;
  #pragma unroll
  for (int m = 1; m < 64; m <<= 1) {
    s += __shfl_xor(s, m, 64);
    s2 += __shfl_xor(s2, m, 64);
  }
  float mu = s * (1.f / 256.f);
  float var = s2 * (1.f / 256.f) - mu * mu;
  float rs = rsqrtf(var + 1e-5f);
  float4 g4 = *(const float4*)(gg + lane * 4);
  float4 b4 = *(const float4*)(bb + lane * 4);
  ushort4 o;
  o.x = f2bf((v.x - mu) * rs * g4.x + b4.x);
  o.y = f2bf((v.y - mu) * rs * g4.y + b4.y);
  o.z = f2bf((v.z - mu) * rs * g4.z + b4.z);
  o.w = f2bf((v.w - mu) * rs * g4.w + b4.w);
  *(ushort4*)(out + (size_t)gw * 256u + lane * 4) = o;
}

// ---------------- GEMM: C = A(MxK bf16) @ Bt^T (Bt is NxK bf16) + epilogue ------
// 128x128 tile, BK=64, 4 waves (2x2), mfma_f32_16x16x32_bf16, XOR-swizzled LDS
// EPI: 0=qkv scatter  1=proj+winrev+residual  2=fc1+gelu  3=fc2+residual
template<int EPI>
__global__ __launch_bounds__(256) void gemm_bf16(
    const u16* __restrict__ A, const u16* __restrict__ Bt,
    int N, int K, int rowOff, const float* __restrict__ bias,
    const float* __restrict__ e0, float* __restrict__ e1,
    u16* __restrict__ o0, u16* __restrict__ o1, u16* __restrict__ o2,
    float* __restrict__ fo) {
  (void)N;
  __shared__ __align__(16) u16 Ab[128 * 64];
  __shared__ __align__(16) u16 Bb[128 * 64];
  const int t = threadIdx.x;
  const int w = t >> 6, lane = t & 63;
  const int wm = w >> 1, wn = w & 1;
  const int g4 = lane >> 4, l15 = lane & 15;
  const int rowBase = blockIdx.y * 128;
  const int colBase = blockIdx.x * 128;
  f32x4 acc[4][4] = {};

  for (int kk = 0; kk < K; kk += 64) {
    __syncthreads();
    #pragma unroll
    for (int i = 0; i < 4; ++i) {
      int chunk = i * 256 + t;
      int row = chunk >> 3, cc = chunk & 7;
      int scc = cc ^ (row & 7);
      gload_lds16(A + (size_t)(rowBase + row) * K + kk + scc * 8,
                  &Ab[(i * 256 + w * 64) * 8]);
    }
    #pragma unroll
    for (int i = 0; i < 4; ++i) {
      int chunk = i * 256 + t;
      int row = chunk >> 3, cc = chunk & 7;
      int scc = cc ^ (row & 7);
      gload_lds16(Bt + (size_t)(colBase + row) * K + kk + scc * 8,
                  &Bb[(i * 256 + w * 64) * 8]);
    }
    __syncthreads();
    #pragma unroll
    for (int k2 = 0; k2 < 2; ++k2) {
      short8 af[4], bf[4];
      const int kb = (k2 * 32 + g4 * 8) * 2;
      #pragma unroll
      for (int m = 0; m < 4; ++m) {
        int row = wm * 64 + m * 16 + l15;
        af[m] = *(const short8*)((const char*)Ab + row * 128 + (kb ^ ((row & 7) << 4)));
      }
      #pragma unroll
      for (int n = 0; n < 4; ++n) {
        int row = wn * 64 + n * 16 + l15;
        bf[n] = *(const short8*)((const char*)Bb + row * 128 + (kb ^ ((row & 7) << 4)));
      }
      #pragma unroll
      for (int m = 0; m < 4; ++m)
        #pragma unroll
        for (int n = 0; n < 4; ++n)
          acc[m][n] = __builtin_amdgcn_mfma_f32_16x16x32_bf16(af[m], bf[n], acc[m][n], 0, 0, 0);
    }
  }

  // epilogue: D layout col = lane&15, row = (lane>>4)*4 + reg
  #pragma unroll
  for (int m = 0; m < 4; ++m) {
    #pragma unroll
    for (int r = 0; r < 4; ++r) {
      int grow = rowBase + wm * 64 + m * 16 + g4 * 4 + r;
      if constexpr (EPI == 0) {
        u32 b_ = (u32)grow / 49u, nn = (u32)grow - b_ * 49u;
        size_t rb = (size_t)b_ * 8u;
        #pragma unroll
        for (int n = 0; n < 4; ++n) {
          int gcol = colBase + wn * 64 + n * 16 + l15;
          float v = acc[m][n][r] + bias[gcol];
          u32 which = (u32)gcol >> 8, hh = ((u32)gcol >> 5) & 7u, dd = (u32)gcol & 31u;
          size_t idx = ((rb + hh) * 49u + nn) * 32u + dd;
          if (which == 0) o0[idx] = f2bf(v * 0.17677669529663687f);
          else if (which == 1) o1[idx] = f2bf(v);
          else o2[idx] = f2bf(v);
        }
      } else if constexpr (EPI == 1) {
        u32 b_ = (u32)grow / 49u, nn = (u32)grow - b_ * 49u;
        u32 bb2 = b_ >> 6, wv = b_ & 63u, wy = wv >> 3, wx = wv & 7u;
        u32 ii = nn / 7u, jj = nn - ii * 7u;
        u32 y = wy * 7u + ii + 3u;   if (y >= 56u) y -= 56u;
        u32 xx = wx * 7u + jj + 3u;  if (xx >= 56u) xx -= 56u;
        size_t tr = ((size_t)bb2 * 3136u + y * 56u + xx) * 256u;
        #pragma unroll
        for (int n = 0; n < 4; ++n) {
          int gcol = colBase + wn * 64 + n * 16 + l15;
          float v = acc[m][n][r] + bias[gcol];
          e1[tr + gcol] = e0[tr + gcol] + v;
        }
      } else if constexpr (EPI == 2) {
        size_t tr = (size_t)grow * 1024u;
        #pragma unroll
        for (int n = 0; n < 4; ++n) {
          int gcol = colBase + wn * 64 + n * 16 + l15;
          float v = acc[m][n][r] + bias[gcol];
          o0[tr + gcol] = f2bf(0.5f * v * (1.0f + erff(v * 0.70710678118654752f)));
        }
      } else {
        size_t tr = ((size_t)(rowOff + grow)) * 256u;
        #pragma unroll
        for (int n = 0; n < 4; ++n) {
          int gcol = colBase + wn * 64 + n * 16 + l15;
          float v = acc[m][n][r] + bias[gcol];
          fo[tr + gcol] = e1[tr + gcol] + v;
        }
      }
    }
  }
}

// ---------------- attention: one wave per (window, head) -----------------------
__global__ __launch_bounds__(64) void attn_kernel(
    const u16* __restrict__ qb, const u16* __restrict__ kb, const u16* __restrict__ vb,
    const float* __restrict__ bm, u16* __restrict__ ao) {
  __shared__ __align__(16) u16 p_lds[64 * 64];
  const int lane = threadIdx.x;
  const int blk = blockIdx.x;
  const int h = blk & 7;
  const int b_ = blk >> 3;
  const int wv = b_ & 63, wy = wv >> 3, wx = wv & 7;
  const int mtype = ((wy == 7) ? 2 : 0) + ((wx == 7) ? 1 : 0);
  const int g4 = lane >> 4, l15 = lane & 15;
  const size_t base = (size_t)(b_ * 8 + h) * 49u * 32u;

  // Q/K fragments straight from global (clamp padded rows to 48)
  short8 qf[4], kf[4];
  #pragma unroll
  for (int i = 0; i < 4; ++i) {
    int rr = i * 16 + l15; if (rr > 48) rr = 48;
    qf[i] = *(const short8*)(qb + base + (size_t)rr * 32u + g4 * 8);
    kf[i] = *(const short8*)(kb + base + (size_t)rr * 32u + g4 * 8);
  }
  // S^T = K @ Q^T : s[m][rb] holds n = m*16+g4*4+reg (key), r = rb*16+l15 (query)
  f32x4 s[4][4] = {};
  #pragma unroll
  for (int m = 0; m < 4; ++m)
    #pragma unroll
    for (int rb = 0; rb < 4; ++rb)
      s[m][rb] = __builtin_amdgcn_mfma_f32_16x16x32_bf16(kf[m], qf[rb], s[m][rb], 0, 0, 0);

  const float* bmh = bm + ((size_t)(mtype * 8 + h)) * 4096u;
  #pragma unroll
  for (int rb = 0; rb < 4; ++rb) {
    int r = rb * 16 + l15;
    #pragma unroll
    for (int m = 0; m < 4; ++m)
      #pragma unroll
      for (int rg = 0; rg < 4; ++rg)
        s[m][rb][rg] += bmh[(m * 16 + g4 * 4 + rg) * 64 + r];
    float mx = -1e30f;
    #pragma unroll
    for (int m = 0; m < 4; ++m)
      #pragma unroll
      for (int rg = 0; rg < 4; ++rg)
        mx = fmaxf(mx, s[m][rb][rg]);
    mx = fmaxf(mx, __shfl_xor(mx, 16, 64));
    mx = fmaxf(mx, __shfl_xor(mx, 32, 64));
    float sum = 0.f;
    #pragma unroll
    for (int m = 0; m < 4; ++m)
      #pragma unroll
      for (int rg = 0; rg < 4; ++rg) {
        float e = __expf(s[m][rb][rg] - mx);
        s[m][rb][rg] = e;
        sum += e;
      }
    sum += __shfl_xor(sum, 16, 64);
    sum += __shfl_xor(sum, 32, 64);
    float inv = 1.0f / sum;
    #pragma unroll
    for (int m = 0; m < 4; ++m)
      #pragma unroll
      for (int rg = 0; rg < 4; ++rg) {
        int nn = m * 16 + g4 * 4 + rg;
        *(u16*)((char*)p_lds + r * 128 + ((nn * 2) ^ ((r & 7) << 4))) = f2bf(s[m][rb][rg] * inv);
      }
  }
  __syncthreads();

  // out = P @ V ; P from swizzled LDS, V strided from global ([n][dd] layout)
  f32x4 o[4][2] = {};
  #pragma unroll
  for (int ks = 0; ks < 2; ++ks) {
    short8 pf[4];
    const int kbyt = (ks * 32 + g4 * 8) * 2;
    #pragma unroll
    for (int ma = 0; ma < 4; ++ma) {
      int r = ma * 16 + l15;
      pf[ma] = *(const short8*)((const char*)p_lds + r * 128 + (kbyt ^ ((r & 7) << 4)));
    }
    short8 vf[2];
    #pragma unroll
    for (int nd = 0; nd < 2; ++nd) {
      int dd = nd * 16 + l15;
      #pragma unroll
      for (int j = 0; j < 8; ++j)
        vf[nd][j] = (short)vb[base + (size_t)(ks * 32 + g4 * 8 + j) * 32u + dd];
    }
    #pragma unroll
    for (int ma = 0; ma < 4; ++ma)
      #pragma unroll
      for (int nd = 0; nd < 2; ++nd)
        o[ma][nd] = __builtin_amdgcn_mfma_f32_16x16x32_bf16(pf[ma], vf[nd], o[ma][nd], 0, 0, 0);
  }
  __syncthreads();
  // stage out rows [64][32] bf16 in LDS, then coalesced global write
  #pragma unroll
  for (int ma = 0; ma < 4; ++ma)
    #pragma unroll
    for (int nd = 0; nd < 2; ++nd)
      #pragma unroll
      for (int rg = 0; rg < 4; ++rg) {
        int r = ma * 16 + g4 * 4 + rg;
        int dd = nd * 16 + l15;
        p_lds[r * 32 + dd] = f2bf(o[ma][nd][rg]);
      }
  __syncthreads();
  #pragma unroll
  for (int i = 0; i < 4; ++i) {
    int chunk = i * 64 + lane;   // 196 chunks of 8 u16
    if (chunk < 196) {
      int row = chunk >> 2, off = (chunk & 3) * 8;
      short8 d = *(const short8*)&p_lds[row * 32 + off];
      *(short8*)(ao + ((size_t)(b_ * 49 + row)) * 256u + h * 32 + off) = d;
    }
  }
}

extern "C" void kernel_launch(void* const* d_in, const int* in_sizes, int n_in,
                              void* d_out, int out_size, void* d_ws, size_t ws_size,
                              hipStream_t stream) {
  (void)in_sizes; (void)n_in; (void)out_size; (void)ws_size;
  const float* x    = (const float*)d_in[0];
  const float* n1g  = (const float*)d_in[1];
  const float* n1b  = (const float*)d_in[2];
  const float* qkvw = (const float*)d_in[3];
  const float* qkvb = (const float*)d_in[4];
  const float* rpb  = (const float*)d_in[5];
  const float* pw   = (const float*)d_in[6];
  const float* pb   = (const float*)d_in[7];
  const float* n2g  = (const float*)d_in[8];
  const float* n2b  = (const float*)d_in[9];
  const float* f1w  = (const float*)d_in[10];
  const float* f1b  = (const float*)d_in[11];
  const float* f2w  = (const float*)d_in[12];
  const float* f2b  = (const float*)d_in[13];
  float* out = (float*)d_out;

  char* ws = (char*)d_ws;
  u16* wA   = (u16*)ws;                       // 102,760,448 B (LN1 out / LN2 out)
  char* r1  = ws + 102760448;
  u16* qbuf = (u16*)r1;                       // each 102,760,448 B
  u16* kbuf = (u16*)(r1 + 102760448);
  u16* vbuf = (u16*)(r1 + 205520896);         // + 64KB tail pad inside region
  u16* hid  = (u16*)r1;                       // reuse for MLP hidden chunks
  char* r2  = r1 + 308346880;
  u16* aout = (u16*)r2;                       // 102,760,448 B
  char* r3  = r2 + 102760448;
  float* x2 = (float*)r3;                     // 205,520,896 B
  char* r4  = r3 + 205520896;
  float* bmtab = (float*)r4;                  // 524,288 B
  char* r5  = r4 + 524288;
  u16* wtq  = (u16*)r5;                       // 393,216 B
  u16* wtp  = (u16*)(r5 + 393216);            // 131,072 B
  u16* wtf1 = (u16*)(r5 + 524288);            // 524,288 B
  u16* wtf2 = (u16*)(r5 + 1048576);           // 524,288 B

  wtrans_kernel<<<768, 256, 0, stream>>>(qkvw, wtq, 256, 768);
  wtrans_kernel<<<256, 256, 0, stream>>>(pw, wtp, 256, 256);
  wtrans_kernel<<<1024, 256, 0, stream>>>(f1w, wtf1, 256, 1024);
  wtrans_kernel<<<1024, 256, 0, stream>>>(f2w, wtf2, 1024, 256);
  biasmask_kernel<<<512, 256, 0, stream>>>(rpb, bmtab);

  ln_kernel<true><<<50176, 256, 0, stream>>>(x, n1g, n1b, wA);
  gemm_bf16<0><<<dim3(6, 1568), 256, 0, stream>>>(wA, wtq, 768, 256, 0, qkvb,
      nullptr, nullptr, qbuf, kbuf, vbuf, nullptr);
  attn_kernel<<<32768, 64, 0, stream>>>(qbuf, kbuf, vbuf, bmtab, aout);
  gemm_bf16<1><<<dim3(2, 1568), 256, 0, stream>>>(aout, wtp, 256, 256, 0, pb,
      x, x2, nullptr, nullptr, nullptr, nullptr);
  ln_kernel<false><<<50176, 256, 0, stream>>>(x2, n2g, n2b, wA);
  for (int c = 0; c < 4; ++c) {
    int r0 = c * 50176;
    gemm_bf16<2><<<dim3(8, 392), 256, 0, stream>>>(wA + (size_t)r0 * 256, wtf1, 1024, 256, r0, f1b,
        nullptr, nullptr, hid, nullptr, nullptr, nullptr);
    gemm_bf16<3><<<dim3(2, 392), 256, 0, stream>>>(hid, wtf2, 256, 1024, r0, f2b,
        nullptr, x2, nullptr, nullptr, nullptr, out);
  }
}

// Round 2
// 1031.202 us; speedup vs baseline: 1.0866x; 1.0866x over previous
//
#include <hip/hip_runtime.h>
#include <hip/hip_bf16.h>

typedef unsigned short u16;
typedef unsigned int u32;
typedef __attribute__((ext_vector_type(8))) short short8;
typedef __attribute__((ext_vector_type(4))) float f32x4;

#define DEVFN static __device__ __forceinline__

DEVFN u16 f2bf(float f) {
  union { float f; u32 i; } v; v.f = f;
  return (u16)((v.i + 0x7fffu + ((v.i >> 16) & 1u)) >> 16);
}
DEVFN float bf2f(u16 u) {
  union { u32 i; float f; } v; v.i = ((u32)u) << 16; return v.f;
}
DEVFN void gload_lds16(const void* g, void* l) {
  __builtin_amdgcn_global_load_lds((const __attribute__((address_space(1))) u32*)g,
                                   (__attribute__((address_space(3))) u32*)l, 16, 0, 0);
}

// ---------------- weight transpose: W (K x N, f32) -> Wt (N x K, bf16) ----------
__global__ void wtrans_kernel(const float* __restrict__ w, u16* __restrict__ wt, int K, int N) {
  int idx = blockIdx.x * 256 + threadIdx.x;
  if (idx >= K * N) return;
  int n = idx / K, k = idx - n * K;
  wt[idx] = f2bf(w[(size_t)k * N + n]);
}

// ---------------- bias+mask table: [4 types][8 heads][64 key][64 query] --------
__global__ void biasmask_kernel(const float* __restrict__ rpb, float* __restrict__ bm) {
  int idx = blockIdx.x * 256 + threadIdx.x;
  if (idx >= 4 * 8 * 64 * 64) return;
  int r = idx & 63;
  int nn = (idx >> 6) & 63;
  int h = (idx >> 12) & 7;
  int t = idx >> 15;
  float v;
  if (nn >= 49) v = -1e9f;
  else if (r >= 49) v = 0.f;
  else {
    int i1 = r / 7, j1 = r - i1 * 7, i2 = nn / 7, j2 = nn - i2 * 7;
    int rel = (i1 - i2 + 6) * 13 + (j1 - j2 + 6);
    v = rpb[rel * 8 + h];
    int ry1 = (t & 2) ? (i1 < 4 ? 1 : 2) : 0;
    int rx1 = (t & 1) ? (j1 < 4 ? 1 : 2) : 0;
    int ry2 = (t & 2) ? (i2 < 4 ? 1 : 2) : 0;
    int rx2 = (t & 1) ? (j2 < 4 ? 1 : 2) : 0;
    if (ry1 * 3 + rx1 != ry2 * 3 + rx2) v += -100.0f;
  }
  bm[idx] = v;
}

// ---------------- LayerNorm1 (one wave per token) with shift+window gather -----
__global__ void ln_kernel(const float* __restrict__ x, const float* __restrict__ gg,
                          const float* __restrict__ bb, u16* __restrict__ out) {
  int gw = (int)(((u32)blockIdx.x * blockDim.x + threadIdx.x) >> 6);
  int lane = threadIdx.x & 63;
  u32 tw = (u32)gw;
  u32 b_ = tw / 49u, nn = tw - b_ * 49u;
  u32 bbi = b_ >> 6, wv = b_ & 63u, wy = wv >> 3, wx = wv & 7u;
  u32 ii = nn / 7u, jj = nn - ii * 7u;
  u32 y = wy * 7u + ii + 3u;  if (y >= 56u) y -= 56u;
  u32 xx = wx * 7u + jj + 3u; if (xx >= 56u) xx -= 56u;
  size_t src = ((size_t)(bbi * 3136u + y * 56u + xx)) * 256u;
  float4 v = *(const float4*)(x + src + lane * 4);
  float s = v.x + v.y + v.z + v.w;
  float s2 = v.x * v.x + v.y * v.y + v.z * v.z + v.w * v.w;
  #pragma unroll
  for (int m = 1; m < 64; m <<= 1) {
    s += __shfl_xor(s, m, 64);
    s2 += __shfl_xor(s2, m, 64);
  }
  float mu = s * (1.f / 256.f);
  float var = s2 * (1.f / 256.f) - mu * mu;
  float rs = rsqrtf(var + 1e-5f);
  float4 g4 = *(const float4*)(gg + lane * 4);
  float4 b4 = *(const float4*)(bb + lane * 4);
  ushort4 o;
  o.x = f2bf((v.x - mu) * rs * g4.x + b4.x);
  o.y = f2bf((v.y - mu) * rs * g4.y + b4.y);
  o.z = f2bf((v.z - mu) * rs * g4.z + b4.z);
  o.w = f2bf((v.w - mu) * rs * g4.w + b4.w);
  *(ushort4*)(out + (size_t)gw * 256u + lane * 4) = o;
}

// ---------------- QKV GEMM: [200704,256]bf16 @ Wt[768,256] -> [200704,768] -----
// BM=128 BN=256 BK=64, 512 threads (8 waves 2x4), row-major output, q-scaled.
__global__ __launch_bounds__(512, 2) void qkv_gemm(
    const u16* __restrict__ A, const u16* __restrict__ Bt,
    const float* __restrict__ bias, u16* __restrict__ C) {
  __shared__ __align__(16) u16 Ab[128 * 64];
  __shared__ __align__(16) u16 Bb[256 * 64];
  const int t = threadIdx.x;
  const int w = t >> 6, lane = t & 63;
  const int wm = w >> 2, wn = w & 3;
  const int g4 = lane >> 4, l15 = lane & 15;
  // XCD-chunked swizzle: 4704 = 8 * 588
  int bid = blockIdx.x;
  int logical = (bid & 7) * 588 + (bid >> 3);
  const int bx = logical % 3, by = logical / 3;
  const int rowBase = by * 128;
  const int colBase = bx * 256;
  f32x4 acc[4][4] = {};

  for (int kk = 0; kk < 256; kk += 64) {
    __syncthreads();
    #pragma unroll
    for (int i = 0; i < 2; ++i) {
      int c = i * 512 + w * 64 + lane;
      int row = c >> 3, cc = c & 7, scc = cc ^ (row & 7);
      gload_lds16(A + (size_t)(rowBase + row) * 256 + kk + scc * 8,
                  &Ab[(i * 512 + w * 64) * 8]);
    }
    #pragma unroll
    for (int i = 0; i < 4; ++i) {
      int c = i * 512 + w * 64 + lane;
      int row = c >> 3, cc = c & 7, scc = cc ^ (row & 7);
      gload_lds16(Bt + (size_t)(colBase + row) * 256 + kk + scc * 8,
                  &Bb[(i * 512 + w * 64) * 8]);
    }
    __syncthreads();
    #pragma unroll
    for (int ks = 0; ks < 2; ++ks) {
      short8 af[4], bf[4];
      const int kb = (ks * 32 + g4 * 8) * 2;
      #pragma unroll
      for (int m = 0; m < 4; ++m) {
        int row = wm * 64 + m * 16 + l15;
        af[m] = *(const short8*)((const char*)Ab + row * 128 + (kb ^ ((row & 7) << 4)));
      }
      #pragma unroll
      for (int n = 0; n < 4; ++n) {
        int row = wn * 64 + n * 16 + l15;
        bf[n] = *(const short8*)((const char*)Bb + row * 128 + (kb ^ ((row & 7) << 4)));
      }
      #pragma unroll
      for (int m = 0; m < 4; ++m)
        #pragma unroll
        for (int n = 0; n < 4; ++n)
          acc[m][n] = __builtin_amdgcn_mfma_f32_16x16x32_bf16(af[m], bf[n], acc[m][n], 0, 0, 0);
    }
  }
  const float scale = (colBase == 0) ? 0.17677669529663687f : 1.0f;
  float bv[4];
  #pragma unroll
  for (int n = 0; n < 4; ++n) bv[n] = bias[colBase + wn * 64 + n * 16 + l15];
  #pragma unroll
  for (int m = 0; m < 4; ++m)
    #pragma unroll
    for (int r = 0; r < 4; ++r) {
      int grow = rowBase + wm * 64 + m * 16 + g4 * 4 + r;
      #pragma unroll
      for (int n = 0; n < 4; ++n) {
        int gcol = colBase + wn * 64 + n * 16 + l15;
        C[(size_t)grow * 768 + gcol] = f2bf((acc[m][n][r] + bv[n]) * scale);
      }
    }
}

// ---------------- mega attention: attn + proj + residual + LN2 per window ------
// 512 threads = 8 waves (wave = head for attention phase).
__global__ __launch_bounds__(512, 2) void attn_mega(
    const u16* __restrict__ qkv, const float* __restrict__ bm,
    const u16* __restrict__ wtp, const float* __restrict__ pbias,
    const float* __restrict__ x, const float* __restrict__ g2,
    const float* __restrict__ b2, u16* __restrict__ x2g,
    u16* __restrict__ lno) {
  __shared__ __align__(16) char smem[140800];   // [0,75264): qkv window; [75264,140800): R2
  char* R2 = smem + 75264;
  const int t = threadIdx.x;
  const int w = t >> 6, lane = t & 63;
  const int g4 = lane >> 4, l15 = lane & 15;
  const int b_ = blockIdx.x;
  const int wv = b_ & 63, wy = wv >> 3, wx = wv & 7;
  const int mtype = ((wy == 7) ? 2 : 0) + ((wx == 7) ? 1 : 0);
  const int h = w;

  // phase A: stage window qkv (49 rows x 1536 B), source-swizzled
  const size_t gbase = (size_t)b_ * 49u * 768u;
  #pragma unroll
  for (int i = 0; i < 10; ++i) {
    int c = i * 512 + w * 64 + lane;
    if (c < 4704) {
      int row = c / 96, cc = c - row * 96;
      int scc = cc ^ (row & 7);
      gload_lds16(qkv + gbase + (size_t)row * 768 + scc * 8,
                  smem + (size_t)(i * 512 + w * 64) * 16);
    }
  }
  __syncthreads();

  // phase B: S^T = K @ Q^T, bias+mask+softmax, P -> LDS
  short8 qf[4], kf[4];
  #pragma unroll
  for (int i = 0; i < 4; ++i) {
    int r = i * 16 + l15; if (r > 48) r = 48;
    int cq = h * 4 + g4;
    int ck = 32 + h * 4 + g4;
    qf[i] = *(const short8*)(smem + r * 1536 + ((cq ^ (r & 7)) << 4));
    kf[i] = *(const short8*)(smem + r * 1536 + ((ck ^ (r & 7)) << 4));
  }
  f32x4 s[4][4] = {};
  #pragma unroll
  for (int m = 0; m < 4; ++m)
    #pragma unroll
    for (int rb = 0; rb < 4; ++rb)
      s[m][rb] = __builtin_amdgcn_mfma_f32_16x16x32_bf16(kf[m], qf[rb], s[m][rb], 0, 0, 0);

  const float* bmh = bm + (size_t)(mtype * 8 + h) * 4096u;
  char* pw = R2 + w * 8192;
  #pragma unroll
  for (int rb = 0; rb < 4; ++rb) {
    int r = rb * 16 + l15;
    #pragma unroll
    for (int m = 0; m < 4; ++m)
      #pragma unroll
      for (int rg = 0; rg < 4; ++rg)
        s[m][rb][rg] += bmh[(m * 16 + g4 * 4 + rg) * 64 + r];
    float mx = -1e30f;
    #pragma unroll
    for (int m = 0; m < 4; ++m)
      #pragma unroll
      for (int rg = 0; rg < 4; ++rg)
        mx = fmaxf(mx, s[m][rb][rg]);
    mx = fmaxf(mx, __shfl_xor(mx, 16, 64));
    mx = fmaxf(mx, __shfl_xor(mx, 32, 64));
    float sum = 0.f;
    #pragma unroll
    for (int m = 0; m < 4; ++m)
      #pragma unroll
      for (int rg = 0; rg < 4; ++rg) {
        float e = __expf(s[m][rb][rg] - mx);
        s[m][rb][rg] = e;
        sum += e;
      }
    sum += __shfl_xor(sum, 16, 64);
    sum += __shfl_xor(sum, 32, 64);
    float inv = 1.0f / sum;
    #pragma unroll
    for (int m = 0; m < 4; ++m)
      #pragma unroll
      for (int rg = 0; rg < 4; ++rg) {
        int nn = m * 16 + g4 * 4 + rg;
        *(u16*)(pw + r * 128 + ((nn * 2) ^ ((r & 7) << 4))) = f2bf(s[m][rb][rg] * inv);
      }
  }

  // PV (P from own-wave LDS, V from window LDS)
  f32x4 o[4][2] = {};
  #pragma unroll
  for (int ks = 0; ks < 2; ++ks) {
    short8 pf[4];
    const int kbyt = (ks * 32 + g4 * 8) * 2;
    #pragma unroll
    for (int ma = 0; ma < 4; ++ma) {
      int r = ma * 16 + l15;
      pf[ma] = *(const short8*)(pw + r * 128 + (kbyt ^ ((r & 7) << 4)));
    }
    short8 vf[2];
    #pragma unroll
    for (int nd = 0; nd < 2; ++nd) {
      int dd = nd * 16 + l15;
      int colb = (512 + h * 32 + dd) * 2;
      #pragma unroll
      for (int j = 0; j < 8; ++j) {
        int n = ks * 32 + g4 * 8 + j; if (n > 48) n = 48;
        vf[nd][j] = *(const short*)(smem + n * 1536 + (colb ^ ((n & 7) << 4)));
      }
    }
    #pragma unroll
    for (int ma = 0; ma < 4; ++ma)
      #pragma unroll
      for (int nd = 0; nd < 2; ++nd)
        o[ma][nd] = __builtin_amdgcn_mfma_f32_16x16x32_bf16(pf[ma], vf[nd], o[ma][nd], 0, 0, 0);
  }
  __syncthreads();   // all PV done before R2 reuse

  // phase C: attnout [64][256] bf16, XOR-swizzled, at R2[0:32768)
  #pragma unroll
  for (int ma = 0; ma < 4; ++ma)
    #pragma unroll
    for (int nd = 0; nd < 2; ++nd)
      #pragma unroll
      for (int rg = 0; rg < 4; ++rg) {
        int r = ma * 16 + g4 * 4 + rg;
        int colb = (h * 32 + nd * 16 + l15) * 2;
        *(u16*)(R2 + r * 512 + (colb ^ ((r & 7) << 4))) = f2bf(o[ma][nd][rg]);
      }
  __syncthreads();

  // phase D: proj GEMM 64x256 = attnout @ Wpt^T
  const int wm2 = w >> 2, wn2 = w & 3;
  f32x4 ap[2][4] = {};
  for (int kk = 0; kk < 256; kk += 64) {
    #pragma unroll
    for (int i = 0; i < 4; ++i) {
      int c = i * 512 + w * 64 + lane;
      int n = c >> 3, cc = c & 7, scc = cc ^ (n & 7);
      gload_lds16(wtp + (size_t)n * 256 + kk + scc * 8,
                  R2 + 32768 + (size_t)(i * 512 + w * 64) * 16);
    }
    __syncthreads();
    #pragma unroll
    for (int ks2 = 0; ks2 < 2; ++ks2) {
      short8 afr[2], bfr[4];
      int k = kk + ks2 * 32 + g4 * 8;
      #pragma unroll
      for (int mf = 0; mf < 2; ++mf) {
        int r = wm2 * 32 + mf * 16 + l15;
        afr[mf] = *(const short8*)(R2 + r * 512 + ((k * 2) ^ ((r & 7) << 4)));
      }
      #pragma unroll
      for (int nf = 0; nf < 4; ++nf) {
        int n = wn2 * 64 + nf * 16 + l15;
        bfr[nf] = *(const short8*)(R2 + 32768 + n * 128 + (((ks2 * 4 + g4) ^ (n & 7)) << 4));
      }
      #pragma unroll
      for (int mf = 0; mf < 2; ++mf)
        #pragma unroll
        for (int nf = 0; nf < 4; ++nf)
          ap[mf][nf] = __builtin_amdgcn_mfma_f32_16x16x32_bf16(afr[mf], bfr[nf], ap[mf][nf], 0, 0, 0);
    }
    __syncthreads();
  }

  // phase E: proj + bias -> x2f fp32 [64][260] in smem[0:...)
  float* x2f = (float*)smem;
  float pb4[4];
  #pragma unroll
  for (int nf = 0; nf < 4; ++nf) pb4[nf] = pbias[wn2 * 64 + nf * 16 + l15];
  #pragma unroll
  for (int mf = 0; mf < 2; ++mf)
    #pragma unroll
    for (int nf = 0; nf < 4; ++nf)
      #pragma unroll
      for (int rg = 0; rg < 4; ++rg) {
        int r = wm2 * 32 + mf * 16 + g4 * 4 + rg;
        int col = wn2 * 64 + nf * 16 + l15;
        x2f[r * 260 + col] = ap[mf][nf][rg] + pb4[nf];
      }
  __syncthreads();

  // phase F: residual + LN2; write x2 (bf16) and ln2out (bf16), window order
  const u32 bbi = (u32)b_ >> 6;
  for (int r = w; r < 49; r += 8) {
    float4 v = *(const float4*)(x2f + r * 260 + lane * 4);
    u32 ii = (u32)r / 7u, jj = (u32)r - ii * 7u;
    u32 y = (u32)wy * 7u + ii + 3u;  if (y >= 56u) y -= 56u;
    u32 xx = (u32)wx * 7u + jj + 3u; if (xx >= 56u) xx -= 56u;
    size_t orowx = ((size_t)(bbi * 3136u + y * 56u + xx)) * 256u;
    float4 xr = *(const float4*)(x + orowx + lane * 4);
    v.x += xr.x; v.y += xr.y; v.z += xr.z; v.w += xr.w;
    float s1 = v.x + v.y + v.z + v.w;
    float s2 = v.x * v.x + v.y * v.y + v.z * v.z + v.w * v.w;
    #pragma unroll
    for (int m = 1; m < 64; m <<= 1) {
      s1 += __shfl_xor(s1, m, 64);
      s2 += __shfl_xor(s2, m, 64);
    }
    float mu = s1 * (1.f / 256.f);
    float var = s2 * (1.f / 256.f) - mu * mu;
    float rs = rsqrtf(var + 1e-5f);
    float4 gg4 = *(const float4*)(g2 + lane * 4);
    float4 bb4 = *(const float4*)(b2 + lane * 4);
    size_t orow = ((size_t)b_ * 49u + r) * 256u + lane * 4;
    ushort4 xo;
    xo.x = f2bf(v.x); xo.y = f2bf(v.y); xo.z = f2bf(v.z); xo.w = f2bf(v.w);
    *(ushort4*)(x2g + orow) = xo;
    ushort4 lo;
    lo.x = f2bf((v.x - mu) * rs * gg4.x + bb4.x);
    lo.y = f2bf((v.y - mu) * rs * gg4.y + bb4.y);
    lo.z = f2bf((v.z - mu) * rs * gg4.z + bb4.z);
    lo.w = f2bf((v.w - mu) * rs * gg4.w + bb4.w);
    *(ushort4*)(lno + orow) = lo;
  }
}

// ---------------- fused MLP: fc1 + gelu + fc2 + residual + un-permute ----------
// 128-row blocks, 512 threads (8 waves 2x4). A kept in LDS; H tiled per ht.
__global__ __launch_bounds__(512, 2) void mlp_mega(
    const u16* __restrict__ A, const u16* __restrict__ w1t,
    const u16* __restrict__ w2t, const float* __restrict__ b1,
    const float* __restrict__ b2f, const u16* __restrict__ x2g,
    float* __restrict__ out) {
  __shared__ __align__(16) char smem[131072];  // A[128][256]@0; H[128][128]@65536; W@98304
  const int t = threadIdx.x;
  const int w = t >> 6, lane = t & 63;
  const int g4 = lane >> 4, l15 = lane & 15;
  const int wm = w >> 2, wn = w & 3;
  const int rowBase = blockIdx.x * 128;

  #pragma unroll
  for (int i = 0; i < 8; ++i) {
    int c = i * 512 + w * 64 + lane;
    int row = c >> 5, cc = c & 31, scc = cc ^ (row & 7);
    gload_lds16(A + (size_t)(rowBase + row) * 256 + scc * 8,
                smem + (size_t)(i * 512 + w * 64) * 16);
  }

  f32x4 accO[4][4] = {};
  for (int ht = 0; ht < 8; ++ht) {
    f32x4 accH[4][2] = {};
    for (int ks = 0; ks < 4; ++ks) {
      __syncthreads();   // prev W readers done (and A-stage drained on first pass)
      #pragma unroll
      for (int i = 0; i < 2; ++i) {
        int c = i * 512 + w * 64 + lane;
        int n = c >> 3, cc = c & 7, scc = cc ^ (n & 7);
        gload_lds16(w1t + (size_t)(ht * 128 + n) * 256 + ks * 64 + scc * 8,
                    smem + 98304 + (size_t)(i * 512 + w * 64) * 16);
      }
      __syncthreads();
      #pragma unroll
      for (int ks2 = 0; ks2 < 2; ++ks2) {
        short8 afr[4], bfr[2];
        int k = ks * 64 + ks2 * 32 + g4 * 8;
        #pragma unroll
        for (int mf = 0; mf < 4; ++mf) {
          int r = wm * 64 + mf * 16 + l15;
          afr[mf] = *(const short8*)(smem + r * 512 + ((k * 2) ^ ((r & 7) << 4)));
        }
        #pragma unroll
        for (int nf = 0; nf < 2; ++nf) {
          int n = wn * 32 + nf * 16 + l15;
          bfr[nf] = *(const short8*)(smem + 98304 + n * 128 + (((ks2 * 4 + g4) ^ (n & 7)) << 4));
        }
        #pragma unroll
        for (int mf = 0; mf < 4; ++mf)
          #pragma unroll
          for (int nf = 0; nf < 2; ++nf)
            accH[mf][nf] = __builtin_amdgcn_mfma_f32_16x16x32_bf16(afr[mf], bfr[nf], accH[mf][nf], 0, 0, 0);
      }
    }
    // H epilogue: bias + exact gelu -> H LDS (swizzled)
    float b1v[2];
    #pragma unroll
    for (int nf = 0; nf < 2; ++nf) b1v[nf] = b1[ht * 128 + wn * 32 + nf * 16 + l15];
    #pragma unroll
    for (int mf = 0; mf < 4; ++mf)
      #pragma unroll
      for (int nf = 0; nf < 2; ++nf)
        #pragma unroll
        for (int rg = 0; rg < 4; ++rg) {
          int r = wm * 64 + mf * 16 + g4 * 4 + rg;
          int col = wn * 32 + nf * 16 + l15;
          float v = accH[mf][nf][rg] + b1v[nf];
          v = 0.5f * v * (1.0f + erff(v * 0.70710678118654752f));
          *(u16*)(smem + 65536 + r * 256 + ((col * 2) ^ ((r & 7) << 4))) = f2bf(v);
        }
    __syncthreads();
    for (int ks3 = 0; ks3 < 2; ++ks3) {
      if (ks3) __syncthreads();
      #pragma unroll
      for (int i = 0; i < 4; ++i) {
        int c = i * 512 + w * 64 + lane;
        int n = c >> 3, cc = c & 7, scc = cc ^ (n & 7);
        gload_lds16(w2t + (size_t)n * 1024 + ht * 128 + ks3 * 64 + scc * 8,
                    smem + 98304 + (size_t)(i * 512 + w * 64) * 16);
      }
      __syncthreads();
      #pragma unroll
      for (int ks2 = 0; ks2 < 2; ++ks2) {
        short8 afr[4], bfr[4];
        int k = ks3 * 64 + ks2 * 32 + g4 * 8;
        #pragma unroll
        for (int mf = 0; mf < 4; ++mf) {
          int r = wm * 64 + mf * 16 + l15;
          afr[mf] = *(const short8*)(smem + 65536 + r * 256 + ((k * 2) ^ ((r & 7) << 4)));
        }
        #pragma unroll
        for (int nf = 0; nf < 4; ++nf) {
          int n = wn * 64 + nf * 16 + l15;
          bfr[nf] = *(const short8*)(smem + 98304 + n * 128 + (((ks2 * 4 + g4) ^ (n & 7)) << 4));
        }
        #pragma unroll
        for (int mf = 0; mf < 4; ++mf)
          #pragma unroll
          for (int nf = 0; nf < 4; ++nf)
            accO[mf][nf] = __builtin_amdgcn_mfma_f32_16x16x32_bf16(afr[mf], bfr[nf], accO[mf][nf], 0, 0, 0);
      }
    }
  }

  // epilogue: + b2 + x2 (bf16), un-permute (winrev+roll) -> out fp32 spatial
  float b2v[4];
  #pragma unroll
  for (int nf = 0; nf < 4; ++nf) b2v[nf] = b2f[wn * 64 + nf * 16 + l15];
  #pragma unroll
  for (int mf = 0; mf < 4; ++mf)
    #pragma unroll
    for (int rg = 0; rg < 4; ++rg) {
      int grow = rowBase + wm * 64 + mf * 16 + g4 * 4 + rg;
      u32 b_ = (u32)grow / 49u, nn = (u32)grow - b_ * 49u;
      u32 bbi = b_ >> 6, wv = b_ & 63u, wy = wv >> 3, wx = wv & 7u;
      u32 ii = nn / 7u, jj = nn - ii * 7u;
      u32 y = wy * 7u + ii + 3u;  if (y >= 56u) y -= 56u;
      u32 xx = wx * 7u + jj + 3u; if (xx >= 56u) xx -= 56u;
      size_t orow = ((size_t)(bbi * 3136u + y * 56u + xx)) * 256u;
      #pragma unroll
      for (int nf = 0; nf < 4; ++nf) {
        int gcol = wn * 64 + nf * 16 + l15;
        float xv = bf2f(x2g[(size_t)grow * 256u + gcol]);
        out[orow + gcol] = accO[mf][nf][rg] + b2v[nf] + xv;
      }
    }
}

extern "C" void kernel_launch(void* const* d_in, const int* in_sizes, int n_in,
                              void* d_out, int out_size, void* d_ws, size_t ws_size,
                              hipStream_t stream) {
  (void)in_sizes; (void)n_in; (void)out_size; (void)ws_size;
  const float* x    = (const float*)d_in[0];
  const float* n1g  = (const float*)d_in[1];
  const float* n1b  = (const float*)d_in[2];
  const float* qkvw = (const float*)d_in[3];
  const float* qkvb = (const float*)d_in[4];
  const float* rpb  = (const float*)d_in[5];
  const float* pw   = (const float*)d_in[6];
  const float* pb   = (const float*)d_in[7];
  const float* n2g  = (const float*)d_in[8];
  const float* n2b  = (const float*)d_in[9];
  const float* f1w  = (const float*)d_in[10];
  const float* f1b  = (const float*)d_in[11];
  const float* f2w  = (const float*)d_in[12];
  const float* f2b  = (const float*)d_in[13];
  float* out = (float*)d_out;

  char* ws = (char*)d_ws;
  u16* wA     = (u16*)ws;                        // 102,760,448 (ln1 out, window order)
  u16* qkvbuf = (u16*)(ws + 102760448);          // 308,281,344 ([200704][768] bf16)
  u16* x2g    = (u16*)(ws + 411041792);          // 102,760,448 (x2, bf16, window order)
  u16* lno    = (u16*)(ws + 513802240);          // 102,760,448 (ln2 out, bf16, window order)
  float* bmtab = (float*)(ws + 616562688);       // 524,288
  u16* wtq  = (u16*)(ws + 617086976);            // 393,216
  u16* wtp  = (u16*)(ws + 617480192);            // 131,072
  u16* wtf1 = (u16*)(ws + 617611264);            // 524,288
  u16* wtf2 = (u16*)(ws + 618135552);            // 524,288

  wtrans_kernel<<<768, 256, 0, stream>>>(qkvw, wtq, 256, 768);
  wtrans_kernel<<<256, 256, 0, stream>>>(pw, wtp, 256, 256);
  wtrans_kernel<<<1024, 256, 0, stream>>>(f1w, wtf1, 256, 1024);
  wtrans_kernel<<<1024, 256, 0, stream>>>(f2w, wtf2, 1024, 256);
  biasmask_kernel<<<512, 256, 0, stream>>>(rpb, bmtab);

  ln_kernel<<<50176, 256, 0, stream>>>(x, n1g, n1b, wA);
  qkv_gemm<<<4704, 512, 0, stream>>>(wA, wtq, qkvb, qkvbuf);
  attn_mega<<<4096, 512, 0, stream>>>(qkvbuf, bmtab, wtp, pb, x, n2g, n2b, x2g, lno);
  mlp_mega<<<1568, 512, 0, stream>>>(lno, wtf1, wtf2, f1b, f2b, x2g, out);
}

// Round 3
// 952.200 us; speedup vs baseline: 1.1767x; 1.0830x over previous
//
#include <hip/hip_runtime.h>
#include <hip/hip_bf16.h>

typedef unsigned short u16;
typedef unsigned int u32;
typedef __attribute__((ext_vector_type(8))) short short8;
typedef __attribute__((ext_vector_type(4))) float f32x4;

#define DEVFN static __device__ __forceinline__

DEVFN u16 f2bf(float f) {
  union { float f; u32 i; } v; v.f = f;
  return (u16)((v.i + 0x7fffu + ((v.i >> 16) & 1u)) >> 16);
}
DEVFN float bf2f(u16 u) {
  union { u32 i; float f; } v; v.i = ((u32)u) << 16; return v.f;
}
DEVFN void gload_lds16(const void* g, void* l) {
  __builtin_amdgcn_global_load_lds((const __attribute__((address_space(1))) u32*)g,
                                   (__attribute__((address_space(3))) u32*)l, 16, 0, 0);
}

// ---------------- weight transpose: W (K x N, f32) -> Wt (N x K, bf16) ----------
__global__ void wtrans_kernel(const float* __restrict__ w, u16* __restrict__ wt, int K, int N) {
  int idx = blockIdx.x * 256 + threadIdx.x;
  if (idx >= K * N) return;
  int n = idx / K, k = idx - n * K;
  wt[idx] = f2bf(w[(size_t)k * N + n]);
}

// ---------------- bias+mask table: [4 types][8 heads][64 key][64 query] --------
__global__ void biasmask_kernel(const float* __restrict__ rpb, float* __restrict__ bm) {
  int idx = blockIdx.x * 256 + threadIdx.x;
  if (idx >= 4 * 8 * 64 * 64) return;
  int r = idx & 63;
  int nn = (idx >> 6) & 63;
  int h = (idx >> 12) & 7;
  int t = idx >> 15;
  float v;
  if (nn >= 49) v = -1e9f;
  else if (r >= 49) v = 0.f;
  else {
    int i1 = r / 7, j1 = r - i1 * 7, i2 = nn / 7, j2 = nn - i2 * 7;
    int rel = (i1 - i2 + 6) * 13 + (j1 - j2 + 6);
    v = rpb[rel * 8 + h];
    int ry1 = (t & 2) ? (i1 < 4 ? 1 : 2) : 0;
    int rx1 = (t & 1) ? (j1 < 4 ? 1 : 2) : 0;
    int ry2 = (t & 2) ? (i2 < 4 ? 1 : 2) : 0;
    int rx2 = (t & 1) ? (j2 < 4 ? 1 : 2) : 0;
    if (ry1 * 3 + rx1 != ry2 * 3 + rx2) v += -100.0f;
  }
  bm[idx] = v;
}

// ---------------- LayerNorm1 (one wave per token) with shift+window gather -----
__global__ void ln_kernel(const float* __restrict__ x, const float* __restrict__ gg,
                          const float* __restrict__ bb, u16* __restrict__ out) {
  int gw = (int)(((u32)blockIdx.x * blockDim.x + threadIdx.x) >> 6);
  int lane = threadIdx.x & 63;
  u32 tw = (u32)gw;
  u32 b_ = tw / 49u, nn = tw - b_ * 49u;
  u32 bbi = b_ >> 6, wv = b_ & 63u, wy = wv >> 3, wx = wv & 7u;
  u32 ii = nn / 7u, jj = nn - ii * 7u;
  u32 y = wy * 7u + ii + 3u;  if (y >= 56u) y -= 56u;
  u32 xx = wx * 7u + jj + 3u; if (xx >= 56u) xx -= 56u;
  size_t src = ((size_t)(bbi * 3136u + y * 56u + xx)) * 256u;
  float4 v = *(const float4*)(x + src + lane * 4);
  float s = v.x + v.y + v.z + v.w;
  float s2 = v.x * v.x + v.y * v.y + v.z * v.z + v.w * v.w;
  #pragma unroll
  for (int m = 1; m < 64; m <<= 1) {
    s += __shfl_xor(s, m, 64);
    s2 += __shfl_xor(s2, m, 64);
  }
  float mu = s * (1.f / 256.f);
  float var = s2 * (1.f / 256.f) - mu * mu;
  float rs = rsqrtf(var + 1e-5f);
  float4 g4 = *(const float4*)(gg + lane * 4);
  float4 b4 = *(const float4*)(bb + lane * 4);
  ushort4 o;
  o.x = f2bf((v.x - mu) * rs * g4.x + b4.x);
  o.y = f2bf((v.y - mu) * rs * g4.y + b4.y);
  o.z = f2bf((v.z - mu) * rs * g4.z + b4.z);
  o.w = f2bf((v.w - mu) * rs * g4.w + b4.w);
  *(ushort4*)(out + (size_t)gw * 256u + lane * 4) = o;
}

// ---------------- QKV GEMM: [200704,256]bf16 @ Wt[768,256] -> [200704,768] -----
__global__ __launch_bounds__(512, 2) void qkv_gemm(
    const u16* __restrict__ A, const u16* __restrict__ Bt,
    const float* __restrict__ bias, u16* __restrict__ C) {
  __shared__ __align__(16) u16 Ab[128 * 64];
  __shared__ __align__(16) u16 Bb[256 * 64];
  const int t = threadIdx.x;
  const int w = t >> 6, lane = t & 63;
  const int wm = w >> 2, wn = w & 3;
  const int g4 = lane >> 4, l15 = lane & 15;
  int bid = blockIdx.x;
  int logical = (bid & 7) * 588 + (bid >> 3);
  const int bx = logical % 3, by = logical / 3;
  const int rowBase = by * 128;
  const int colBase = bx * 256;
  f32x4 acc[4][4] = {};

  for (int kk = 0; kk < 256; kk += 64) {
    __syncthreads();
    #pragma unroll
    for (int i = 0; i < 2; ++i) {
      int c = i * 512 + w * 64 + lane;
      int row = c >> 3, cc = c & 7, scc = cc ^ (row & 7);
      gload_lds16(A + (size_t)(rowBase + row) * 256 + kk + scc * 8,
                  &Ab[(i * 512 + w * 64) * 8]);
    }
    #pragma unroll
    for (int i = 0; i < 4; ++i) {
      int c = i * 512 + w * 64 + lane;
      int row = c >> 3, cc = c & 7, scc = cc ^ (row & 7);
      gload_lds16(Bt + (size_t)(colBase + row) * 256 + kk + scc * 8,
                  &Bb[(i * 512 + w * 64) * 8]);
    }
    __syncthreads();
    #pragma unroll
    for (int ks = 0; ks < 2; ++ks) {
      short8 af[4], bf[4];
      const int kb = (ks * 32 + g4 * 8) * 2;
      #pragma unroll
      for (int m = 0; m < 4; ++m) {
        int row = wm * 64 + m * 16 + l15;
        af[m] = *(const short8*)((const char*)Ab + row * 128 + (kb ^ ((row & 7) << 4)));
      }
      #pragma unroll
      for (int n = 0; n < 4; ++n) {
        int row = wn * 64 + n * 16 + l15;
        bf[n] = *(const short8*)((const char*)Bb + row * 128 + (kb ^ ((row & 7) << 4)));
      }
      #pragma unroll
      for (int m = 0; m < 4; ++m)
        #pragma unroll
        for (int n = 0; n < 4; ++n)
          acc[m][n] = __builtin_amdgcn_mfma_f32_16x16x32_bf16(af[m], bf[n], acc[m][n], 0, 0, 0);
    }
  }
  const float scale = (colBase == 0) ? 0.17677669529663687f : 1.0f;
  float bv[4];
  #pragma unroll
  for (int n = 0; n < 4; ++n) bv[n] = bias[colBase + wn * 64 + n * 16 + l15];
  #pragma unroll
  for (int m = 0; m < 4; ++m)
    #pragma unroll
    for (int r = 0; r < 4; ++r) {
      int grow = rowBase + wm * 64 + m * 16 + g4 * 4 + r;
      #pragma unroll
      for (int n = 0; n < 4; ++n) {
        int gcol = colBase + wn * 64 + n * 16 + l15;
        C[(size_t)grow * 768 + gcol] = f2bf((acc[m][n][r] + bv[n]) * scale);
      }
    }
}

// ---------------- mega attention: attn + proj + residual + LN2 per window ------
__global__ __launch_bounds__(512, 2) void attn_mega(
    const u16* __restrict__ qkv, const float* __restrict__ bm,
    const u16* __restrict__ wtp, const float* __restrict__ pbias,
    const float* __restrict__ x, const float* __restrict__ g2,
    const float* __restrict__ b2, u16* __restrict__ x2g,
    u16* __restrict__ lno) {
  __shared__ __align__(16) char smem[140800];   // [0,75264): qkv window; [75264,140800): R2
  char* R2 = smem + 75264;
  const int t = threadIdx.x;
  const int w = t >> 6, lane = t & 63;
  const int g4 = lane >> 4, l15 = lane & 15;
  const int b_ = blockIdx.x;
  const int wv = b_ & 63, wy = wv >> 3, wx = wv & 7;
  const int mtype = ((wy == 7) ? 2 : 0) + ((wx == 7) ? 1 : 0);
  const int h = w;

  const size_t gbase = (size_t)b_ * 49u * 768u;
  #pragma unroll
  for (int i = 0; i < 10; ++i) {
    int c = i * 512 + w * 64 + lane;
    if (c < 4704) {
      int row = c / 96, cc = c - row * 96;
      int scc = cc ^ (row & 7);
      gload_lds16(qkv + gbase + (size_t)row * 768 + scc * 8,
                  smem + (size_t)(i * 512 + w * 64) * 16);
    }
  }
  __syncthreads();

  short8 qf[4], kf[4];
  #pragma unroll
  for (int i = 0; i < 4; ++i) {
    int r = i * 16 + l15; if (r > 48) r = 48;
    int cq = h * 4 + g4;
    int ck = 32 + h * 4 + g4;
    qf[i] = *(const short8*)(smem + r * 1536 + ((cq ^ (r & 7)) << 4));
    kf[i] = *(const short8*)(smem + r * 1536 + ((ck ^ (r & 7)) << 4));
  }
  f32x4 s[4][4] = {};
  #pragma unroll
  for (int m = 0; m < 4; ++m)
    #pragma unroll
    for (int rb = 0; rb < 4; ++rb)
      s[m][rb] = __builtin_amdgcn_mfma_f32_16x16x32_bf16(kf[m], qf[rb], s[m][rb], 0, 0, 0);

  const float* bmh = bm + (size_t)(mtype * 8 + h) * 4096u;
  char* pw = R2 + w * 8192;
  #pragma unroll
  for (int rb = 0; rb < 4; ++rb) {
    int r = rb * 16 + l15;
    #pragma unroll
    for (int m = 0; m < 4; ++m)
      #pragma unroll
      for (int rg = 0; rg < 4; ++rg)
        s[m][rb][rg] += bmh[(m * 16 + g4 * 4 + rg) * 64 + r];
    float mx = -1e30f;
    #pragma unroll
    for (int m = 0; m < 4; ++m)
      #pragma unroll
      for (int rg = 0; rg < 4; ++rg)
        mx = fmaxf(mx, s[m][rb][rg]);
    mx = fmaxf(mx, __shfl_xor(mx, 16, 64));
    mx = fmaxf(mx, __shfl_xor(mx, 32, 64));
    float sum = 0.f;
    #pragma unroll
    for (int m = 0; m < 4; ++m)
      #pragma unroll
      for (int rg = 0; rg < 4; ++rg) {
        float e = __expf(s[m][rb][rg] - mx);
        s[m][rb][rg] = e;
        sum += e;
      }
    sum += __shfl_xor(sum, 16, 64);
    sum += __shfl_xor(sum, 32, 64);
    float inv = 1.0f / sum;
    #pragma unroll
    for (int m = 0; m < 4; ++m)
      #pragma unroll
      for (int rg = 0; rg < 4; ++rg) {
        int nn = m * 16 + g4 * 4 + rg;
        *(u16*)(pw + r * 128 + ((nn * 2) ^ ((r & 7) << 4))) = f2bf(s[m][rb][rg] * inv);
      }
  }

  f32x4 o[4][2] = {};
  #pragma unroll
  for (int ks = 0; ks < 2; ++ks) {
    short8 pf[4];
    const int kbyt = (ks * 32 + g4 * 8) * 2;
    #pragma unroll
    for (int ma = 0; ma < 4; ++ma) {
      int r = ma * 16 + l15;
      pf[ma] = *(const short8*)(pw + r * 128 + (kbyt ^ ((r & 7) << 4)));
    }
    short8 vf[2];
    #pragma unroll
    for (int nd = 0; nd < 2; ++nd) {
      int dd = nd * 16 + l15;
      int colb = (512 + h * 32 + dd) * 2;
      #pragma unroll
      for (int j = 0; j < 8; ++j) {
        int n = ks * 32 + g4 * 8 + j; if (n > 48) n = 48;
        vf[nd][j] = *(const short*)(smem + n * 1536 + (colb ^ ((n & 7) << 4)));
      }
    }
    #pragma unroll
    for (int ma = 0; ma < 4; ++ma)
      #pragma unroll
      for (int nd = 0; nd < 2; ++nd)
        o[ma][nd] = __builtin_amdgcn_mfma_f32_16x16x32_bf16(pf[ma], vf[nd], o[ma][nd], 0, 0, 0);
  }
  __syncthreads();

  #pragma unroll
  for (int ma = 0; ma < 4; ++ma)
    #pragma unroll
    for (int nd = 0; nd < 2; ++nd)
      #pragma unroll
      for (int rg = 0; rg < 4; ++rg) {
        int r = ma * 16 + g4 * 4 + rg;
        int colb = (h * 32 + nd * 16 + l15) * 2;
        *(u16*)(R2 + r * 512 + (colb ^ ((r & 7) << 4))) = f2bf(o[ma][nd][rg]);
      }
  __syncthreads();

  const int wm2 = w >> 2, wn2 = w & 3;
  f32x4 ap[2][4] = {};
  for (int kk = 0; kk < 256; kk += 64) {
    #pragma unroll
    for (int i = 0; i < 4; ++i) {
      int c = i * 512 + w * 64 + lane;
      int n = c >> 3, cc = c & 7, scc = cc ^ (n & 7);
      gload_lds16(wtp + (size_t)n * 256 + kk + scc * 8,
                  R2 + 32768 + (size_t)(i * 512 + w * 64) * 16);
    }
    __syncthreads();
    #pragma unroll
    for (int ks2 = 0; ks2 < 2; ++ks2) {
      short8 afr[2], bfr[4];
      int k = kk + ks2 * 32 + g4 * 8;
      #pragma unroll
      for (int mf = 0; mf < 2; ++mf) {
        int r = wm2 * 32 + mf * 16 + l15;
        afr[mf] = *(const short8*)(R2 + r * 512 + ((k * 2) ^ ((r & 7) << 4)));
      }
      #pragma unroll
      for (int nf = 0; nf < 4; ++nf) {
        int n = wn2 * 64 + nf * 16 + l15;
        bfr[nf] = *(const short8*)(R2 + 32768 + n * 128 + (((ks2 * 4 + g4) ^ (n & 7)) << 4));
      }
      #pragma unroll
      for (int mf = 0; mf < 2; ++mf)
        #pragma unroll
        for (int nf = 0; nf < 4; ++nf)
          ap[mf][nf] = __builtin_amdgcn_mfma_f32_16x16x32_bf16(afr[mf], bfr[nf], ap[mf][nf], 0, 0, 0);
    }
    __syncthreads();
  }

  float* x2f = (float*)smem;
  float pb4[4];
  #pragma unroll
  for (int nf = 0; nf < 4; ++nf) pb4[nf] = pbias[wn2 * 64 + nf * 16 + l15];
  #pragma unroll
  for (int mf = 0; mf < 2; ++mf)
    #pragma unroll
    for (int nf = 0; nf < 4; ++nf)
      #pragma unroll
      for (int rg = 0; rg < 4; ++rg) {
        int r = wm2 * 32 + mf * 16 + g4 * 4 + rg;
        int col = wn2 * 64 + nf * 16 + l15;
        x2f[r * 260 + col] = ap[mf][nf][rg] + pb4[nf];
      }
  __syncthreads();

  const u32 bbi = (u32)b_ >> 6;
  for (int r = w; r < 49; r += 8) {
    float4 v = *(const float4*)(x2f + r * 260 + lane * 4);
    u32 ii = (u32)r / 7u, jj = (u32)r - ii * 7u;
    u32 y = (u32)wy * 7u + ii + 3u;  if (y >= 56u) y -= 56u;
    u32 xx = (u32)wx * 7u + jj + 3u; if (xx >= 56u) xx -= 56u;
    size_t orowx = ((size_t)(bbi * 3136u + y * 56u + xx)) * 256u;
    float4 xr = *(const float4*)(x + orowx + lane * 4);
    v.x += xr.x; v.y += xr.y; v.z += xr.z; v.w += xr.w;
    float s1 = v.x + v.y + v.z + v.w;
    float s2 = v.x * v.x + v.y * v.y + v.z * v.z + v.w * v.w;
    #pragma unroll
    for (int m = 1; m < 64; m <<= 1) {
      s1 += __shfl_xor(s1, m, 64);
      s2 += __shfl_xor(s2, m, 64);
    }
    float mu = s1 * (1.f / 256.f);
    float var = s2 * (1.f / 256.f) - mu * mu;
    float rs = rsqrtf(var + 1e-5f);
    float4 gg4 = *(const float4*)(g2 + lane * 4);
    float4 bb4 = *(const float4*)(b2 + lane * 4);
    size_t orow = ((size_t)b_ * 49u + r) * 256u + lane * 4;
    ushort4 xo;
    xo.x = f2bf(v.x); xo.y = f2bf(v.y); xo.z = f2bf(v.z); xo.w = f2bf(v.w);
    *(ushort4*)(x2g + orow) = xo;
    ushort4 lo;
    lo.x = f2bf((v.x - mu) * rs * gg4.x + bb4.x);
    lo.y = f2bf((v.y - mu) * rs * gg4.y + bb4.y);
    lo.z = f2bf((v.z - mu) * rs * gg4.z + bb4.z);
    lo.w = f2bf((v.w - mu) * rs * gg4.w + bb4.w);
    *(ushort4*)(lno + orow) = lo;
  }
}

// ---------------- MLP GEMMs: m97-structure, BM=128 BN=256, 8 waves -------------
// EPI 0: fc1 -> bias + exact gelu -> bf16 hid (row stride 1024)
// EPI 1: fc2 -> bias + x2 residual + un-permute -> fp32 out
template<int EPI>
__global__ __launch_bounds__(512, 2) void mlp_gemm(
    const u16* __restrict__ A, const u16* __restrict__ Bt, int K, int nbx,
    const float* __restrict__ bias, const u16* __restrict__ x2g,
    u16* __restrict__ ho, float* __restrict__ out) {
  __shared__ __align__(16) u16 Ab[128 * 64];
  __shared__ __align__(16) u16 Bb[256 * 64];
  const int t = threadIdx.x;
  const int w = t >> 6, lane = t & 63;
  const int wm = w >> 2, wn = w & 3;
  const int g4 = lane >> 4, l15 = lane & 15;
  int bid = blockIdx.x;
  int chunk = (int)gridDim.x >> 3;
  int logical = (bid & 7) * chunk + (bid >> 3);
  const int bx = logical % nbx, by = logical / nbx;
  const int rowBase = by * 128;
  const int colBase = bx * 256;
  f32x4 acc[4][4] = {};

  for (int kk = 0; kk < K; kk += 64) {
    __syncthreads();
    #pragma unroll
    for (int i = 0; i < 2; ++i) {
      int c = i * 512 + w * 64 + lane;
      int row = c >> 3, cc = c & 7, scc = cc ^ (row & 7);
      gload_lds16(A + (size_t)(rowBase + row) * K + kk + scc * 8,
                  &Ab[(i * 512 + w * 64) * 8]);
    }
    #pragma unroll
    for (int i = 0; i < 4; ++i) {
      int c = i * 512 + w * 64 + lane;
      int row = c >> 3, cc = c & 7, scc = cc ^ (row & 7);
      gload_lds16(Bt + (size_t)(colBase + row) * K + kk + scc * 8,
                  &Bb[(i * 512 + w * 64) * 8]);
    }
    __syncthreads();
    #pragma unroll
    for (int ks = 0; ks < 2; ++ks) {
      short8 af[4], bf[4];
      const int kb = (ks * 32 + g4 * 8) * 2;
      #pragma unroll
      for (int m = 0; m < 4; ++m) {
        int row = wm * 64 + m * 16 + l15;
        af[m] = *(const short8*)((const char*)Ab + row * 128 + (kb ^ ((row & 7) << 4)));
      }
      #pragma unroll
      for (int n = 0; n < 4; ++n) {
        int row = wn * 64 + n * 16 + l15;
        bf[n] = *(const short8*)((const char*)Bb + row * 128 + (kb ^ ((row & 7) << 4)));
      }
      #pragma unroll
      for (int m = 0; m < 4; ++m)
        #pragma unroll
        for (int n = 0; n < 4; ++n)
          acc[m][n] = __builtin_amdgcn_mfma_f32_16x16x32_bf16(af[m], bf[n], acc[m][n], 0, 0, 0);
    }
  }

  float bv[4];
  #pragma unroll
  for (int n = 0; n < 4; ++n) bv[n] = bias[colBase + wn * 64 + n * 16 + l15];
  #pragma unroll
  for (int m = 0; m < 4; ++m)
    #pragma unroll
    for (int r = 0; r < 4; ++r) {
      int grow = rowBase + wm * 64 + m * 16 + g4 * 4 + r;
      if constexpr (EPI == 0) {
        #pragma unroll
        for (int n = 0; n < 4; ++n) {
          int gcol = colBase + wn * 64 + n * 16 + l15;
          float v = acc[m][n][r] + bv[n];
          v = 0.5f * v * (1.0f + erff(v * 0.70710678118654752f));
          ho[(size_t)grow * 1024u + gcol] = f2bf(v);
        }
      } else {
        u32 b_ = (u32)grow / 49u, nn = (u32)grow - b_ * 49u;
        u32 bbi = b_ >> 6, wv = b_ & 63u, wy = wv >> 3, wx = wv & 7u;
        u32 ii = nn / 7u, jj = nn - ii * 7u;
        u32 y = wy * 7u + ii + 3u;  if (y >= 56u) y -= 56u;
        u32 xx = wx * 7u + jj + 3u; if (xx >= 56u) xx -= 56u;
        size_t orow = ((size_t)(bbi * 3136u + y * 56u + xx)) * 256u;
        #pragma unroll
        for (int n = 0; n < 4; ++n) {
          int gcol = colBase + wn * 64 + n * 16 + l15;
          float xv = bf2f(x2g[(size_t)grow * 256u + gcol]);
          out[orow + gcol] = acc[m][n][r] + bv[n] + xv;
        }
      }
    }
}

extern "C" void kernel_launch(void* const* d_in, const int* in_sizes, int n_in,
                              void* d_out, int out_size, void* d_ws, size_t ws_size,
                              hipStream_t stream) {
  (void)in_sizes; (void)n_in; (void)out_size; (void)ws_size;
  const float* x    = (const float*)d_in[0];
  const float* n1g  = (const float*)d_in[1];
  const float* n1b  = (const float*)d_in[2];
  const float* qkvw = (const float*)d_in[3];
  const float* qkvb = (const float*)d_in[4];
  const float* rpb  = (const float*)d_in[5];
  const float* pw   = (const float*)d_in[6];
  const float* pb   = (const float*)d_in[7];
  const float* n2g  = (const float*)d_in[8];
  const float* n2b  = (const float*)d_in[9];
  const float* f1w  = (const float*)d_in[10];
  const float* f1b  = (const float*)d_in[11];
  const float* f2w  = (const float*)d_in[12];
  const float* f2b  = (const float*)d_in[13];
  float* out = (float*)d_out;

  char* ws = (char*)d_ws;
  u16* wA     = (u16*)ws;                        // 102,760,448 (ln1 out)
  u16* qkvbuf = (u16*)(ws + 102760448);          // 308,281,344
  u16* hid    = (u16*)ws;                        // 411,041,792 — overlays wA+qkvbuf (dead after attn)
  u16* x2g    = (u16*)(ws + 411041792);          // 102,760,448 (x2, bf16, window order)
  u16* lno    = (u16*)(ws + 513802240);          // 102,760,448 (ln2 out, bf16, window order)
  float* bmtab = (float*)(ws + 616562688);       // 524,288
  u16* wtq  = (u16*)(ws + 617086976);            // 393,216
  u16* wtp  = (u16*)(ws + 617480192);            // 131,072
  u16* wtf1 = (u16*)(ws + 617611264);            // 524,288
  u16* wtf2 = (u16*)(ws + 618135552);            // 524,288

  wtrans_kernel<<<768, 256, 0, stream>>>(qkvw, wtq, 256, 768);
  wtrans_kernel<<<256, 256, 0, stream>>>(pw, wtp, 256, 256);
  wtrans_kernel<<<1024, 256, 0, stream>>>(f1w, wtf1, 256, 1024);
  wtrans_kernel<<<1024, 256, 0, stream>>>(f2w, wtf2, 1024, 256);
  biasmask_kernel<<<512, 256, 0, stream>>>(rpb, bmtab);

  ln_kernel<<<50176, 256, 0, stream>>>(x, n1g, n1b, wA);
  qkv_gemm<<<4704, 512, 0, stream>>>(wA, wtq, qkvb, qkvbuf);
  attn_mega<<<4096, 512, 0, stream>>>(qkvbuf, bmtab, wtp, pb, x, n2g, n2b, x2g, lno);
  mlp_gemm<0><<<6272, 512, 0, stream>>>(lno, wtf1, 256, 4, f1b, nullptr, hid, nullptr);
  mlp_gemm<1><<<1568, 512, 0, stream>>>(hid, wtf2, 1024, 1, f2b, x2g, nullptr, out);
}

// Round 4
// 918.591 us; speedup vs baseline: 1.2198x; 1.0366x over previous
//
#include <hip/hip_runtime.h>
#include <hip/hip_bf16.h>

typedef unsigned short u16;
typedef unsigned int u32;
typedef __attribute__((ext_vector_type(8))) short short8;
typedef __attribute__((ext_vector_type(4))) float f32x4;

#define DEVFN static __device__ __forceinline__

DEVFN u16 f2bf(float f) {
  union { float f; u32 i; } v; v.f = f;
  return (u16)((v.i + 0x7fffu + ((v.i >> 16) & 1u)) >> 16);
}
DEVFN float bf2f(u16 u) {
  union { u32 i; float f; } v; v.i = ((u32)u) << 16; return v.f;
}
DEVFN void gload_lds16(const void* g, void* l) {
  __builtin_amdgcn_global_load_lds((const __attribute__((address_space(1))) u32*)g,
                                   (__attribute__((address_space(3))) u32*)l, 16, 0, 0);
}

// ---------------- weight transpose: W (K x N, f32) -> Wt (N x K, bf16) ----------
__global__ void wtrans_kernel(const float* __restrict__ w, u16* __restrict__ wt, int K, int N) {
  int idx = blockIdx.x * 256 + threadIdx.x;
  if (idx >= K * N) return;
  int n = idx / K, k = idx - n * K;
  wt[idx] = f2bf(w[(size_t)k * N + n]);
}

// ---------------- bias+mask table: [4 types][8 heads][64 key][64 query] --------
__global__ void biasmask_kernel(const float* __restrict__ rpb, float* __restrict__ bm) {
  int idx = blockIdx.x * 256 + threadIdx.x;
  if (idx >= 4 * 8 * 64 * 64) return;
  int r = idx & 63;
  int nn = (idx >> 6) & 63;
  int h = (idx >> 12) & 7;
  int t = idx >> 15;
  float v;
  if (nn >= 49) v = -1e9f;
  else if (r >= 49) v = 0.f;
  else {
    int i1 = r / 7, j1 = r - i1 * 7, i2 = nn / 7, j2 = nn - i2 * 7;
    int rel = (i1 - i2 + 6) * 13 + (j1 - j2 + 6);
    v = rpb[rel * 8 + h];
    int ry1 = (t & 2) ? (i1 < 4 ? 1 : 2) : 0;
    int rx1 = (t & 1) ? (j1 < 4 ? 1 : 2) : 0;
    int ry2 = (t & 2) ? (i2 < 4 ? 1 : 2) : 0;
    int rx2 = (t & 1) ? (j2 < 4 ? 1 : 2) : 0;
    if (ry1 * 3 + rx1 != ry2 * 3 + rx2) v += -100.0f;
  }
  bm[idx] = v;
}

// ---------------- LayerNorm1 (one wave per token) with shift+window gather -----
__global__ void ln_kernel(const float* __restrict__ x, const float* __restrict__ gg,
                          const float* __restrict__ bb, u16* __restrict__ out) {
  int gw = (int)(((u32)blockIdx.x * blockDim.x + threadIdx.x) >> 6);
  int lane = threadIdx.x & 63;
  u32 tw = (u32)gw;
  u32 b_ = tw / 49u, nn = tw - b_ * 49u;
  u32 bbi = b_ >> 6, wv = b_ & 63u, wy = wv >> 3, wx = wv & 7u;
  u32 ii = nn / 7u, jj = nn - ii * 7u;
  u32 y = wy * 7u + ii + 3u;  if (y >= 56u) y -= 56u;
  u32 xx = wx * 7u + jj + 3u; if (xx >= 56u) xx -= 56u;
  size_t src = ((size_t)(bbi * 3136u + y * 56u + xx)) * 256u;
  float4 v = *(const float4*)(x + src + lane * 4);
  float s = v.x + v.y + v.z + v.w;
  float s2 = v.x * v.x + v.y * v.y + v.z * v.z + v.w * v.w;
  #pragma unroll
  for (int m = 1; m < 64; m <<= 1) {
    s += __shfl_xor(s, m, 64);
    s2 += __shfl_xor(s2, m, 64);
  }
  float mu = s * (1.f / 256.f);
  float var = s2 * (1.f / 256.f) - mu * mu;
  float rs = rsqrtf(var + 1e-5f);
  float4 g4 = *(const float4*)(gg + lane * 4);
  float4 b4 = *(const float4*)(bb + lane * 4);
  ushort4 o;
  o.x = f2bf((v.x - mu) * rs * g4.x + b4.x);
  o.y = f2bf((v.y - mu) * rs * g4.y + b4.y);
  o.z = f2bf((v.z - mu) * rs * g4.z + b4.z);
  o.w = f2bf((v.w - mu) * rs * g4.w + b4.w);
  *(ushort4*)(out + (size_t)gw * 256u + lane * 4) = o;
}

// ---------------- QKV GEMM: [200704,256]bf16 @ Wt[768,256] -> [200704,768] -----
__global__ __launch_bounds__(512, 2) void qkv_gemm(
    const u16* __restrict__ A, const u16* __restrict__ Bt,
    const float* __restrict__ bias, u16* __restrict__ C) {
  __shared__ __align__(16) u16 Ab[128 * 64];
  __shared__ __align__(16) u16 Bb[256 * 64];
  const int t = threadIdx.x;
  const int w = t >> 6, lane = t & 63;
  const int wm = w >> 2, wn = w & 3;
  const int g4 = lane >> 4, l15 = lane & 15;
  int bid = blockIdx.x;
  int logical = (bid & 7) * 588 + (bid >> 3);
  const int bx = logical % 3, by = logical / 3;
  const int rowBase = by * 128;
  const int colBase = bx * 256;
  f32x4 acc[4][4] = {};

  for (int kk = 0; kk < 256; kk += 64) {
    __syncthreads();
    #pragma unroll
    for (int i = 0; i < 2; ++i) {
      int c = i * 512 + w * 64 + lane;
      int row = c >> 3, cc = c & 7, scc = cc ^ (row & 7);
      gload_lds16(A + (size_t)(rowBase + row) * 256 + kk + scc * 8,
                  &Ab[(i * 512 + w * 64) * 8]);
    }
    #pragma unroll
    for (int i = 0; i < 4; ++i) {
      int c = i * 512 + w * 64 + lane;
      int row = c >> 3, cc = c & 7, scc = cc ^ (row & 7);
      gload_lds16(Bt + (size_t)(colBase + row) * 256 + kk + scc * 8,
                  &Bb[(i * 512 + w * 64) * 8]);
    }
    __syncthreads();
    #pragma unroll
    for (int ks = 0; ks < 2; ++ks) {
      short8 af[4], bf[4];
      const int kb = (ks * 32 + g4 * 8) * 2;
      #pragma unroll
      for (int m = 0; m < 4; ++m) {
        int row = wm * 64 + m * 16 + l15;
        af[m] = *(const short8*)((const char*)Ab + row * 128 + (kb ^ ((row & 7) << 4)));
      }
      #pragma unroll
      for (int n = 0; n < 4; ++n) {
        int row = wn * 64 + n * 16 + l15;
        bf[n] = *(const short8*)((const char*)Bb + row * 128 + (kb ^ ((row & 7) << 4)));
      }
      #pragma unroll
      for (int m = 0; m < 4; ++m)
        #pragma unroll
        for (int n = 0; n < 4; ++n)
          acc[m][n] = __builtin_amdgcn_mfma_f32_16x16x32_bf16(af[m], bf[n], acc[m][n], 0, 0, 0);
    }
  }
  const float scale = (colBase == 0) ? 0.17677669529663687f : 1.0f;
  float bv[4];
  #pragma unroll
  for (int n = 0; n < 4; ++n) bv[n] = bias[colBase + wn * 64 + n * 16 + l15];
  #pragma unroll
  for (int m = 0; m < 4; ++m)
    #pragma unroll
    for (int r = 0; r < 4; ++r) {
      int grow = rowBase + wm * 64 + m * 16 + g4 * 4 + r;
      #pragma unroll
      for (int n = 0; n < 4; ++n) {
        int gcol = colBase + wn * 64 + n * 16 + l15;
        C[(size_t)grow * 768 + gcol] = f2bf((acc[m][n][r] + bv[n]) * scale);
      }
    }
}

// ---------------- mega attention: attn + proj + residual + LN2 per window ------
// 512 threads = 8 waves (wave = head). LDS 66KB -> 2 blocks/CU.
__global__ __launch_bounds__(512, 4) void attn_mega(
    const u16* __restrict__ qkv, const float* __restrict__ bm,
    const u16* __restrict__ wtp, const float* __restrict__ pbias,
    const float* __restrict__ x, const float* __restrict__ g2,
    const float* __restrict__ b2, u16* __restrict__ x2g,
    u16* __restrict__ lno) {
  __shared__ __align__(16) char smem[65536];      // P (8x8KB) -> attnout[0,32K)+wstage[32K,64K)
  __shared__ __align__(16) float redbuf[64][4][2];
  const int t = threadIdx.x;
  const int w = t >> 6, lane = t & 63;
  const int g4 = lane >> 4, l15 = lane & 15;
  const int b_ = blockIdx.x;
  const int wv = b_ & 63, wy = wv >> 3, wx = wv & 7;
  const int mtype = ((wy == 7) ? 2 : 0) + ((wx == 7) ? 1 : 0);
  const int h = w;
  const size_t gbase = (size_t)b_ * 49u * 768u;

  // Q/K fragments direct from global (row-major qkv, clamp padded rows to 48)
  short8 qf[4], kf[4];
  #pragma unroll
  for (int i = 0; i < 4; ++i) {
    int r = i * 16 + l15; if (r > 48) r = 48;
    qf[i] = *(const short8*)(qkv + gbase + (size_t)r * 768 + h * 32 + g4 * 8);
    kf[i] = *(const short8*)(qkv + gbase + (size_t)r * 768 + 256 + h * 32 + g4 * 8);
  }
  // S^T = K @ Q^T : s[m][rb] holds key n = m*16+g4*4+reg, query r = rb*16+l15
  f32x4 s[4][4] = {};
  #pragma unroll
  for (int m = 0; m < 4; ++m)
    #pragma unroll
    for (int rb = 0; rb < 4; ++rb)
      s[m][rb] = __builtin_amdgcn_mfma_f32_16x16x32_bf16(kf[m], qf[rb], s[m][rb], 0, 0, 0);

  const float* bmh = bm + (size_t)(mtype * 8 + h) * 4096u;
  char* pw = smem + w * 8192;
  #pragma unroll
  for (int rb = 0; rb < 4; ++rb) {
    int r = rb * 16 + l15;
    #pragma unroll
    for (int m = 0; m < 4; ++m)
      #pragma unroll
      for (int rg = 0; rg < 4; ++rg)
        s[m][rb][rg] += bmh[(m * 16 + g4 * 4 + rg) * 64 + r];
    float mx = -1e30f;
    #pragma unroll
    for (int m = 0; m < 4; ++m)
      #pragma unroll
      for (int rg = 0; rg < 4; ++rg)
        mx = fmaxf(mx, s[m][rb][rg]);
    mx = fmaxf(mx, __shfl_xor(mx, 16, 64));
    mx = fmaxf(mx, __shfl_xor(mx, 32, 64));
    float sum = 0.f;
    #pragma unroll
    for (int m = 0; m < 4; ++m)
      #pragma unroll
      for (int rg = 0; rg < 4; ++rg) {
        float e = __expf(s[m][rb][rg] - mx);
        s[m][rb][rg] = e;
        sum += e;
      }
    sum += __shfl_xor(sum, 16, 64);
    sum += __shfl_xor(sum, 32, 64);
    float inv = 1.0f / sum;
    #pragma unroll
    for (int m = 0; m < 4; ++m)
      #pragma unroll
      for (int rg = 0; rg < 4; ++rg) {
        int nn = m * 16 + g4 * 4 + rg;
        *(u16*)(pw + r * 128 + ((nn * 2) ^ ((r & 7) << 4))) = f2bf(s[m][rb][rg] * inv);
      }
  }

  // PV: P from own-wave LDS, V elements direct from global
  f32x4 o[4][2] = {};
  #pragma unroll
  for (int ks = 0; ks < 2; ++ks) {
    short8 pf[4];
    const int kbyt = (ks * 32 + g4 * 8) * 2;
    #pragma unroll
    for (int ma = 0; ma < 4; ++ma) {
      int r = ma * 16 + l15;
      pf[ma] = *(const short8*)(pw + r * 128 + (kbyt ^ ((r & 7) << 4)));
    }
    short8 vf[2];
    #pragma unroll
    for (int nd = 0; nd < 2; ++nd) {
      int dd = nd * 16 + l15;
      #pragma unroll
      for (int j = 0; j < 8; ++j) {
        int n = ks * 32 + g4 * 8 + j; if (n > 48) n = 48;
        vf[nd][j] = (short)qkv[gbase + (size_t)n * 768 + 512 + h * 32 + dd];
      }
    }
    #pragma unroll
    for (int ma = 0; ma < 4; ++ma)
      #pragma unroll
      for (int nd = 0; nd < 2; ++nd)
        o[ma][nd] = __builtin_amdgcn_mfma_f32_16x16x32_bf16(pf[ma], vf[nd], o[ma][nd], 0, 0, 0);
  }
  __syncthreads();   // all PV done; P region is reused below

  // attnout [64][512B] bf16, XOR-swizzled, at smem[0,32768)
  #pragma unroll
  for (int ma = 0; ma < 4; ++ma)
    #pragma unroll
    for (int nd = 0; nd < 2; ++nd)
      #pragma unroll
      for (int rg = 0; rg < 4; ++rg) {
        int r = ma * 16 + g4 * 4 + rg;
        int colb = (h * 32 + nd * 16 + l15) * 2;
        *(u16*)(smem + r * 512 + (colb ^ ((r & 7) << 4))) = f2bf(o[ma][nd][rg]);
      }
  __syncthreads();

  // proj GEMM 64x256 = attnout @ Wpt^T, weight stage at smem[32768,65536)
  const int wm2 = w >> 2, wn2 = w & 3;
  f32x4 ap[2][4] = {};
  for (int kk = 0; kk < 256; kk += 64) {
    #pragma unroll
    for (int i = 0; i < 4; ++i) {
      int c = i * 512 + w * 64 + lane;
      int n = c >> 3, cc = c & 7, scc = cc ^ (n & 7);
      gload_lds16(wtp + (size_t)n * 256 + kk + scc * 8,
                  smem + 32768 + (size_t)(i * 512 + w * 64) * 16);
    }
    __syncthreads();
    #pragma unroll
    for (int ks2 = 0; ks2 < 2; ++ks2) {
      short8 afr[2], bfr[4];
      int k = kk + ks2 * 32 + g4 * 8;
      #pragma unroll
      for (int mf = 0; mf < 2; ++mf) {
        int r = wm2 * 32 + mf * 16 + l15;
        afr[mf] = *(const short8*)(smem + r * 512 + ((k * 2) ^ ((r & 7) << 4)));
      }
      #pragma unroll
      for (int nf = 0; nf < 4; ++nf) {
        int n = wn2 * 64 + nf * 16 + l15;
        bfr[nf] = *(const short8*)(smem + 32768 + n * 128 + (((ks2 * 4 + g4) ^ (n & 7)) << 4));
      }
      #pragma unroll
      for (int mf = 0; mf < 2; ++mf)
        #pragma unroll
        for (int nf = 0; nf < 4; ++nf)
          ap[mf][nf] = __builtin_amdgcn_mfma_f32_16x16x32_bf16(afr[mf], bfr[nf], ap[mf][nf], 0, 0, 0);
    }
    __syncthreads();
  }

  // epilogue in registers: +bias +x residual, per-row LN2 stats via shuffle+LDS
  float pb4[4];
  #pragma unroll
  for (int nf = 0; nf < 4; ++nf) pb4[nf] = pbias[wn2 * 64 + nf * 16 + l15];
  const u32 bbi = (u32)b_ >> 6;
  float vv[2][4][4];   // [mf][nf][rg] — all indices compile-time after unroll
  #pragma unroll
  for (int mf = 0; mf < 2; ++mf)
    #pragma unroll
    for (int rg = 0; rg < 4; ++rg) {
      int r = wm2 * 32 + mf * 16 + g4 * 4 + rg;
      u32 ii = (u32)r / 7u, jj = (u32)r - ii * 7u;
      u32 y = (u32)wy * 7u + ii + 3u;  if (y >= 56u) y -= 56u;
      u32 xx = (u32)wx * 7u + jj + 3u; if (xx >= 56u) xx -= 56u;
      size_t orowx = ((size_t)(bbi * 3136u + y * 56u + xx)) * 256u;
      float s1 = 0.f, s2 = 0.f;
      #pragma unroll
      for (int nf = 0; nf < 4; ++nf) {
        int col = wn2 * 64 + nf * 16 + l15;
        float v = ap[mf][nf][rg] + pb4[nf] + x[orowx + col];
        vv[mf][nf][rg] = v;
        s1 += v; s2 += v * v;
      }
      #pragma unroll
      for (int m2 = 1; m2 < 16; m2 <<= 1) {
        s1 += __shfl_xor(s1, m2, 64);
        s2 += __shfl_xor(s2, m2, 64);
      }
      if (l15 == 0) { redbuf[r][wn2][0] = s1; redbuf[r][wn2][1] = s2; }
    }
  __syncthreads();
  #pragma unroll
  for (int mf = 0; mf < 2; ++mf)
    #pragma unroll
    for (int rg = 0; rg < 4; ++rg) {
      int r = wm2 * 32 + mf * 16 + g4 * 4 + rg;
      if (r < 49) {
        float s1 = redbuf[r][0][0] + redbuf[r][1][0] + redbuf[r][2][0] + redbuf[r][3][0];
        float s2 = redbuf[r][0][1] + redbuf[r][1][1] + redbuf[r][2][1] + redbuf[r][3][1];
        float mu = s1 * (1.f / 256.f);
        float var = s2 * (1.f / 256.f) - mu * mu;
        float rs = rsqrtf(var + 1e-5f);
        size_t orow = ((size_t)b_ * 49u + r) * 256u;
        #pragma unroll
        for (int nf = 0; nf < 4; ++nf) {
          int col = wn2 * 64 + nf * 16 + l15;
          float v = vv[mf][nf][rg];
          x2g[orow + col] = f2bf(v);
          lno[orow + col] = f2bf((v - mu) * rs * g2[col] + b2[col]);
        }
      }
    }
}

// ---------------- MLP GEMMs: m97-structure, BM=128 BN=256, 8 waves -------------
// EPI 0: fc1 -> bias + exact gelu -> bf16 hid (row stride 1024)
// EPI 1: fc2 -> bias + x2 residual + un-permute -> fp32 out
template<int EPI>
__global__ __launch_bounds__(512, 2) void mlp_gemm(
    const u16* __restrict__ A, const u16* __restrict__ Bt, int K, int nbx,
    const float* __restrict__ bias, const u16* __restrict__ x2g,
    u16* __restrict__ ho, float* __restrict__ out) {
  __shared__ __align__(16) u16 Ab[128 * 64];
  __shared__ __align__(16) u16 Bb[256 * 64];
  const int t = threadIdx.x;
  const int w = t >> 6, lane = t & 63;
  const int wm = w >> 2, wn = w & 3;
  const int g4 = lane >> 4, l15 = lane & 15;
  int bid = blockIdx.x;
  int chunk = (int)gridDim.x >> 3;
  int logical = (bid & 7) * chunk + (bid >> 3);
  const int bx = logical % nbx, by = logical / nbx;
  const int rowBase = by * 128;
  const int colBase = bx * 256;
  f32x4 acc[4][4] = {};

  for (int kk = 0; kk < K; kk += 64) {
    __syncthreads();
    #pragma unroll
    for (int i = 0; i < 2; ++i) {
      int c = i * 512 + w * 64 + lane;
      int row = c >> 3, cc = c & 7, scc = cc ^ (row & 7);
      gload_lds16(A + (size_t)(rowBase + row) * K + kk + scc * 8,
                  &Ab[(i * 512 + w * 64) * 8]);
    }
    #pragma unroll
    for (int i = 0; i < 4; ++i) {
      int c = i * 512 + w * 64 + lane;
      int row = c >> 3, cc = c & 7, scc = cc ^ (row & 7);
      gload_lds16(Bt + (size_t)(colBase + row) * K + kk + scc * 8,
                  &Bb[(i * 512 + w * 64) * 8]);
    }
    __syncthreads();
    #pragma unroll
    for (int ks = 0; ks < 2; ++ks) {
      short8 af[4], bf[4];
      const int kb = (ks * 32 + g4 * 8) * 2;
      #pragma unroll
      for (int m = 0; m < 4; ++m) {
        int row = wm * 64 + m * 16 + l15;
        af[m] = *(const short8*)((const char*)Ab + row * 128 + (kb ^ ((row & 7) << 4)));
      }
      #pragma unroll
      for (int n = 0; n < 4; ++n) {
        int row = wn * 64 + n * 16 + l15;
        bf[n] = *(const short8*)((const char*)Bb + row * 128 + (kb ^ ((row & 7) << 4)));
      }
      #pragma unroll
      for (int m = 0; m < 4; ++m)
        #pragma unroll
        for (int n = 0; n < 4; ++n)
          acc[m][n] = __builtin_amdgcn_mfma_f32_16x16x32_bf16(af[m], bf[n], acc[m][n], 0, 0, 0);
    }
  }

  float bv[4];
  #pragma unroll
  for (int n = 0; n < 4; ++n) bv[n] = bias[colBase + wn * 64 + n * 16 + l15];
  #pragma unroll
  for (int m = 0; m < 4; ++m)
    #pragma unroll
    for (int r = 0; r < 4; ++r) {
      int grow = rowBase + wm * 64 + m * 16 + g4 * 4 + r;
      if constexpr (EPI == 0) {
        #pragma unroll
        for (int n = 0; n < 4; ++n) {
          int gcol = colBase + wn * 64 + n * 16 + l15;
          float v = acc[m][n][r] + bv[n];
          v = 0.5f * v * (1.0f + erff(v * 0.70710678118654752f));
          ho[(size_t)grow * 1024u + gcol] = f2bf(v);
        }
      } else {
        u32 b_ = (u32)grow / 49u, nn = (u32)grow - b_ * 49u;
        u32 bbi = b_ >> 6, wv = b_ & 63u, wy = wv >> 3, wx = wv & 7u;
        u32 ii = nn / 7u, jj = nn - ii * 7u;
        u32 y = wy * 7u + ii + 3u;  if (y >= 56u) y -= 56u;
        u32 xx = wx * 7u + jj + 3u; if (xx >= 56u) xx -= 56u;
        size_t orow = ((size_t)(bbi * 3136u + y * 56u + xx)) * 256u;
        #pragma unroll
        for (int n = 0; n < 4; ++n) {
          int gcol = colBase + wn * 64 + n * 16 + l15;
          float xv = bf2f(x2g[(size_t)grow * 256u + gcol]);
          out[orow + gcol] = acc[m][n][r] + bv[n] + xv;
        }
      }
    }
}

extern "C" void kernel_launch(void* const* d_in, const int* in_sizes, int n_in,
                              void* d_out, int out_size, void* d_ws, size_t ws_size,
                              hipStream_t stream) {
  (void)in_sizes; (void)n_in; (void)out_size; (void)ws_size;
  const float* x    = (const float*)d_in[0];
  const float* n1g  = (const float*)d_in[1];
  const float* n1b  = (const float*)d_in[2];
  const float* qkvw = (const float*)d_in[3];
  const float* qkvb = (const float*)d_in[4];
  const float* rpb  = (const float*)d_in[5];
  const float* pw   = (const float*)d_in[6];
  const float* pb   = (const float*)d_in[7];
  const float* n2g  = (const float*)d_in[8];
  const float* n2b  = (const float*)d_in[9];
  const float* f1w  = (const float*)d_in[10];
  const float* f1b  = (const float*)d_in[11];
  const float* f2w  = (const float*)d_in[12];
  const float* f2b  = (const float*)d_in[13];
  float* out = (float*)d_out;

  char* ws = (char*)d_ws;
  u16* wA     = (u16*)ws;                        // 102,760,448 (ln1 out)
  u16* qkvbuf = (u16*)(ws + 102760448);          // 308,281,344
  u16* hid    = (u16*)ws;                        // 411,041,792 — overlays wA+qkvbuf (dead after attn)
  u16* x2g    = (u16*)(ws + 411041792);          // 102,760,448 (x2, bf16, window order)
  u16* lno    = (u16*)(ws + 513802240);          // 102,760,448 (ln2 out, bf16, window order)
  float* bmtab = (float*)(ws + 616562688);       // 524,288
  u16* wtq  = (u16*)(ws + 617086976);            // 393,216
  u16* wtp  = (u16*)(ws + 617480192);            // 131,072
  u16* wtf1 = (u16*)(ws + 617611264);            // 524,288
  u16* wtf2 = (u16*)(ws + 618135552);            // 524,288

  wtrans_kernel<<<768, 256, 0, stream>>>(qkvw, wtq, 256, 768);
  wtrans_kernel<<<256, 256, 0, stream>>>(pw, wtp, 256, 256);
  wtrans_kernel<<<1024, 256, 0, stream>>>(f1w, wtf1, 256, 1024);
  wtrans_kernel<<<1024, 256, 0, stream>>>(f2w, wtf2, 1024, 256);
  biasmask_kernel<<<512, 256, 0, stream>>>(rpb, bmtab);

  ln_kernel<<<50176, 256, 0, stream>>>(x, n1g, n1b, wA);
  qkv_gemm<<<4704, 512, 0, stream>>>(wA, wtq, qkvb, qkvbuf);
  attn_mega<<<4096, 512, 0, stream>>>(qkvbuf, bmtab, wtp, pb, x, n2g, n2b, x2g, lno);
  mlp_gemm<0><<<6272, 512, 0, stream>>>(lno, wtf1, 256, 4, f1b, nullptr, hid, nullptr);
  mlp_gemm<1><<<1568, 512, 0, stream>>>(hid, wtf2, 1024, 1, f2b, x2g, nullptr, out);
}